// Round 3
// baseline (29881.677 us; speedup 1.0000x reference)
//
#include <hip/hip_runtime.h>

#define KNBR 32
#define NCELL 4096        // 16^3 Morton cells
#define MAXCHUNK 320      // ceil(20000/64)=313 <= 320
#define FCAP (MAXCHUNK * 64)
#define FT 768            // fps threads: 12 waves
#define NWAVE (FT / 64)   // 12
#define NSLOT 27          // chunks per wave: 27*12 = 324 >= 313 (clustered mapping)
#define NP 14             // float2 pairs per array (slot 27 = sentinel pad)
#define NG 4              // slot groups: {0-7, 8-15, 16-23, 24-26}

typedef unsigned long long u64;
typedef unsigned int u32;
typedef float f32x2 __attribute__((ext_vector_type(2)));

// Reference-matching squared distance: ((dx*dx + dy*dy) + dz*dz), no FMA contraction.
__device__ __forceinline__ float sq_dist_nofma(float px, float py, float pz,
                                               float cx, float cy, float cz) {
    float dx = __fsub_rn(px, cx);
    float dy = __fsub_rn(py, cy);
    float dz = __fsub_rn(pz, cz);
    return __fadd_rn(__fadd_rn(__fmul_rn(dx, dx), __fmul_rn(dy, dy)), __fmul_rn(dz, dz));
}

__device__ __forceinline__ unsigned spread4(unsigned v) {
    return (v & 1u) | ((v & 2u) << 2) | ((v & 4u) << 4) | ((v & 8u) << 6);
}

// Canonical CDNA wave64 u32 max-reduction via DPP; lane 63 holds the max;
// readlane broadcasts. Out-of-pattern lanes contribute 0 (identity for unsigned max).
template<int CTRL, int RM>
__device__ __forceinline__ u32 dppmax_step(u32 v) {
    u32 t = (u32)__builtin_amdgcn_update_dpp(0, (int)v, CTRL, RM, 0xf, false);
    return t > v ? t : v;
}
__device__ __forceinline__ u32 wave_max_u32(u32 v) {
    v = dppmax_step<0x111, 0xf>(v);   // row_shr:1
    v = dppmax_step<0x112, 0xf>(v);   // row_shr:2
    v = dppmax_step<0x114, 0xf>(v);   // row_shr:4
    v = dppmax_step<0x118, 0xf>(v);   // row_shr:8
    v = dppmax_step<0x142, 0xa>(v);   // row_bcast:15 -> rows 1,3
    v = dppmax_step<0x143, 0xc>(v);   // row_bcast:31 -> rows 2,3
    return (u32)__builtin_amdgcn_readlane((int)v, 63);
}

// branchless 5-way take
__device__ __forceinline__ void take5(bool t, u32& bh, u32& bl, float& bx, float& by, float& bz,
                                      u32 nh, u32 nl, float nx, float ny, float nz) {
    bh = t ? nh : bh; bl = t ? nl : bl;
    bx = t ? nx : bx; by = t ? ny : by; bz = t ? nz : bz;
}

// K1: AoS -> SoA + norms + Morton cell id + within-cell rank (counting-sort pass 1)
__global__ void prep_kernel(const float* __restrict__ coord, int N,
                            float* __restrict__ sx, float* __restrict__ sy,
                            float* __restrict__ sz, float* __restrict__ sn,
                            int* __restrict__ cell, int* __restrict__ rank,
                            int* __restrict__ hist) {
    int i = blockIdx.x * blockDim.x + threadIdx.x;
    if (i < N) {
        float x = coord[3 * i + 0];
        float y = coord[3 * i + 1];
        float z = coord[3 * i + 2];
        sx[i] = x; sy[i] = y; sz[i] = z;
        sn[i] = __fadd_rn(__fadd_rn(__fmul_rn(x, x), __fmul_rn(y, y)), __fmul_rn(z, z));
        int ix = (int)(x * 16.0f); ix = ix < 0 ? 0 : (ix > 15 ? 15 : ix);
        int iy = (int)(y * 16.0f); iy = iy < 0 ? 0 : (iy > 15 ? 15 : iy);
        int iz = (int)(z * 16.0f); iz = iz < 0 ? 0 : (iz > 15 ? 15 : iz);
        unsigned mc = spread4(ix) | (spread4(iy) << 1) | (spread4(iz) << 2);
        cell[i] = (int)mc;
        rank[i] = atomicAdd(&hist[mc], 1);
    }
}

// K2: exclusive scan of 4096-bin histogram
__global__ __launch_bounds__(1024) void scan_kernel(const int* __restrict__ hist,
                                                    int* __restrict__ cellstart) {
    __shared__ int buf[1024];
    int t = threadIdx.x;
    int h0 = hist[4 * t], h1 = hist[4 * t + 1], h2 = hist[4 * t + 2], h3 = hist[4 * t + 3];
    int s = h0 + h1 + h2 + h3;
    buf[t] = s;
    __syncthreads();
    for (int off = 1; off < 1024; off <<= 1) {
        int v = (t >= off) ? buf[t - off] : 0;
        __syncthreads();
        buf[t] += v;
        __syncthreads();
    }
    int ex = buf[t] - s;
    cellstart[4 * t]     = ex;
    cellstart[4 * t + 1] = ex + h0;
    cellstart[4 * t + 2] = ex + h0 + h1;
    cellstart[4 * t + 3] = ex + h0 + h1 + h2;
}

// K3: scatter into Morton order, packed as (x, y, z, orig_idx_bits)
__global__ void scatter_kernel(const float* __restrict__ sx, const float* __restrict__ sy,
                               const float* __restrict__ sz,
                               const int* __restrict__ cell, const int* __restrict__ rank,
                               const int* __restrict__ cellstart, int N,
                               float4* __restrict__ pts) {
    int i = blockIdx.x * blockDim.x + threadIdx.x;
    if (i < N) {
        int pos = cellstart[cell[i]] + rank[i];
        pts[pos] = make_float4(sx[i], sy[i], sz[i], __int_as_float(i));
    }
}

// K3b: sentinel padding
__global__ void pad_kernel(float4* __restrict__ pts, int N, int cap) {
    int i = N + blockIdx.x * blockDim.x + threadIdx.x;
    if (i < cap) pts[i] = make_float4(1e18f, 1e18f, 1e18f, __int_as_float(0x7fffffff));
}

// K4: chunked FPS, round-15: BRANCHLESS throughput design, no pruning.
// State: 27 slots/thread packed as float2 pairs (pk-math capable); slot r of
// wave wv = chunk wv*27+r (clustered -> spatially-local changes hit few groups),
// lane's point pos = chunk*64+lane = BL + r*64.
// Per step per wave: (1) refold per-lane argmax only for slot-groups whose
// ballot-OR changed last step (4 cached group maxima); (2) merge 4 + ONE
// 2-phase DPP wave-max; first max lane writes key+coords to LDS; (3) barrier;
// (4) 12-entry tree scan (coords carried); (5) branchless pk dist pass over
// all 27 slots: md = min(md, d), group change ballots accumulated.
// Key = mdbits(32) | (0x7FFF-orig)<<17 | pos(15): max => (max md, min orig);
// sentinels (md=0, s15=0) can never win while any md>0 exists.
__global__ __launch_bounds__(FT, 3)
void fps_kernel(const float4* __restrict__ pts,
                const float* __restrict__ coord,
                int nchunk, int n_dst, int* __restrict__ out_idx) {
#pragma clang fp contract(off)
    __shared__ u64    wwin[2][NWAVE];
    __shared__ float4 wcoord[2][NWAVE];

    const int tid = threadIdx.x, lane = tid & 63, wv = tid / 64;
    const float c0x = coord[0], c0y = coord[1], c0z = coord[2];
    const u32 BL = (u32)(wv * (NSLOT * 64) + lane);   // pos = BL + r*64

    // ---- register-resident point state ----
    f32x2 px2[NP], py2[NP], pz2[NP], md2[NP];
    u32   po[NP];                       // two 15-bit (0x7FFF-orig) fields; sentinel=0

    #pragma unroll
    for (int i = 0; i < NP; ++i) {
        float xs0 = 0.f, ys0 = 0.f, zs0 = 0.f, ms0 = 0.f; u32 ss0 = 0;
        float xs1 = 0.f, ys1 = 0.f, zs1 = 0.f, ms1 = 0.f; u32 ss1 = 0;
        {
            int r = 2 * i, c = wv * NSLOT + r;
            if (r < NSLOT && c < nchunk) {
                float4 P = pts[(c << 6) + lane];
                int orig = __float_as_int(P.w);
                xs0 = P.x; ys0 = P.y; zs0 = P.z;
                if (orig != 0x7fffffff) {
                    ss0 = 0x7FFFu - (u32)orig;
                    ms0 = sq_dist_nofma(P.x, P.y, P.z, c0x, c0y, c0z);
                }
            }
        }
        {
            int r = 2 * i + 1, c = wv * NSLOT + r;
            if (r < NSLOT && c < nchunk) {
                float4 P = pts[(c << 6) + lane];
                int orig = __float_as_int(P.w);
                xs1 = P.x; ys1 = P.y; zs1 = P.z;
                if (orig != 0x7fffffff) {
                    ss1 = 0x7FFFu - (u32)orig;
                    ms1 = sq_dist_nofma(P.x, P.y, P.z, c0x, c0y, c0z);
                }
            }
        }
        px2[i].x = xs0; px2[i].y = xs1;
        py2[i].x = ys0; py2[i].y = ys1;
        pz2[i].x = zs0; pz2[i].y = zs1;
        md2[i].x = ms0; md2[i].y = ms1;
        po[i] = ss0 | (ss1 << 16);
    }

    // per-lane per-group cached argmax (key hi, key lo, coords)
    u32 gh[NG], gl[NG]; float gx[NG], gy[NG], gz[NG];
    u64 accg[NG];
    #pragma unroll
    for (int g = 0; g < NG; ++g) { gh[g] = 0; gl[g] = 0; gx[g] = gy[g] = gz[g] = 0.f;
                                   accg[g] = ~0ull; }   // force full fold at s=1

    if (tid == 0) out_idx[0] = 0;

    int par = 1;
    for (int s = 1; s < n_dst; ++s) {
        // (1) refold changed groups (wave-uniform branches)
        #pragma unroll
        for (int g = 0; g < NG; ++g) {
            if (accg[g]) {
                const int r0 = g * 8;
                const int r1 = (g == NG - 1) ? NSLOT : (r0 + 8);
                u32 bh = 0, bl = 0; float bx = 0.f, by = 0.f, bz = 0.f;
                #pragma unroll
                for (int r = r0; r < r1; ++r) {
                    const int i = r >> 1, h = r & 1;
                    u32 nh  = __float_as_uint(h ? md2[i].y : md2[i].x);
                    u32 s15 = h ? (po[i] >> 16) : (po[i] & 0xFFFFu);
                    u32 nl  = (s15 << 17) + (BL + (u32)(r * 64));
                    float nx = h ? px2[i].y : px2[i].x;
                    float ny = h ? py2[i].y : py2[i].x;
                    float nz = h ? pz2[i].y : pz2[i].x;
                    bool t = (nh > bh) || (nh == bh && nl > bl);
                    take5(t, bh, bl, bx, by, bz, nh, nl, nx, ny, nz);
                }
                gh[g] = bh; gl[g] = bl; gx[g] = bx; gy[g] = by; gz[g] = bz;
            }
        }
        // (2) merge 4 groups + wave DPP max
        u32 whi = gh[0], wlo = gl[0]; float wx = gx[0], wy = gy[0], wz = gz[0];
        #pragma unroll
        for (int g = 1; g < NG; ++g) {
            bool t = (gh[g] > whi) || (gh[g] == whi && gl[g] > wlo);
            take5(t, whi, wlo, wx, wy, wz, gh[g], gl[g], gx[g], gy[g], gz[g]);
        }
        u32 mhi = wave_max_u32(whi);
        u64 tb = __ballot(whi == mhi);
        u32 mlo;
        if (__popcll(tb) == 1) {
            mlo = (u32)__builtin_amdgcn_readlane((int)wlo, (int)(__ffsll((long long)tb) - 1));
        } else {
            mlo = wave_max_u32(whi == mhi ? wlo : 0u);
        }
        u64 tb2 = __ballot(whi == mhi && wlo == mlo);
        if (lane == (int)(__ffsll((long long)tb2) - 1)) {
            wwin[par][wv]   = ((u64)mhi << 32) | mlo;
            wcoord[par][wv] = make_float4(wx, wy, wz, 0.f);
        }
        __syncthreads();                    // the ONLY barrier per step

        // (4) 12-entry tree scan, coords carried
        u64 kk[NWAVE]; float4 cc[NWAVE];
        #pragma unroll
        for (int w2 = 0; w2 < NWAVE; ++w2) { kk[w2] = wwin[par][w2]; cc[w2] = wcoord[par][w2]; }
        #define TAKEW(A, B) { bool t_ = kk[B] > kk[A]; \
            kk[A] = t_ ? kk[B] : kk[A]; \
            cc[A].x = t_ ? cc[B].x : cc[A].x; \
            cc[A].y = t_ ? cc[B].y : cc[A].y; \
            cc[A].z = t_ ? cc[B].z : cc[A].z; }
        TAKEW(0, 1)  TAKEW(2, 3)  TAKEW(4, 5)  TAKEW(6, 7)  TAKEW(8, 9)  TAKEW(10, 11)
        TAKEW(0, 2)  TAKEW(4, 6)  TAKEW(8, 10)
        TAKEW(0, 4)  TAKEW(0, 8)
        #undef TAKEW
        u64 kb = kk[0];
        if (tid == 0) out_idx[s] = (int)(0x7FFFu - (u32)((kb >> 17) & 0x7FFFull));
        par ^= 1;

        // (5) branchless pk dist pass over all 27 slots
        f32x2 nx2; nx2.x = cc[0].x; nx2.y = cc[0].x;
        f32x2 ny2; ny2.x = cc[0].y; ny2.y = cc[0].y;
        f32x2 nz2; nz2.x = cc[0].z; nz2.y = cc[0].z;
        #pragma unroll
        for (int g = 0; g < NG; ++g) accg[g] = 0ull;
        #pragma unroll
        for (int i = 0; i < NP; ++i) {
            f32x2 dx = px2[i] - nx2;
            f32x2 dy = py2[i] - ny2;
            f32x2 dz = pz2[i] - nz2;
            f32x2 dd = (dx * dx + dy * dy) + dz * dz;   // contract(off): exact order
            bool ca = dd.x < md2[i].x;
            bool cb = dd.y < md2[i].y;
            accg[i >> 2] |= __ballot(ca) | __ballot(cb);
            md2[i].x = ca ? dd.x : md2[i].x;
            md2[i].y = cb ? dd.y : md2[i].y;
        }
    }
}

// K5: ball query, one wave per dst. First K in-radius src indices in ascending order.
__global__ void ball_kernel(const float* __restrict__ sx, const float* __restrict__ sy,
                            const float* __restrict__ sz, const float* __restrict__ sn,
                            const int* __restrict__ idx,
                            const float* __restrict__ coord, const int* __restrict__ batch,
                            int N, int n_dst,
                            float* __restrict__ out_coord, float* __restrict__ out_esrc,
                            float* __restrict__ out_edst, float* __restrict__ out_deg,
                            float* __restrict__ out_batch,
                            int* __restrict__ nbr_i, int* __restrict__ deg_i) {
    const int d    = blockIdx.x;
    const int lane = threadIdx.x;   // block of 64
    __shared__ int nbr[KNBR];

    const int id = idx[d];
    const float cx = sx[id], cy = sy[id], cz = sz[id];
    const float dn = sn[id];
    const float RR = (float)(0.08 * 0.08);

    int cnt = 0;
    for (int base = 0; base < N && cnt < KNBR; base += 64) {
        int i = base + lane;
        bool in = false;
        if (i < N) {
            float t     = __fmul_rn(sx[i], cx);
            float inner = __fmaf_rn(sy[i], cy, t);
            inner       = __fmaf_rn(sz[i], cz, inner);
            float d2    = __fsub_rn(__fadd_rn(dn, sn[i]), __fmul_rn(2.0f, inner));
            in = (d2 <= RR);
        }
        unsigned long long m = __ballot(in);
        int pos = cnt + __popcll(m & ((1ull << lane) - 1ull));
        if (in && pos < KNBR) nbr[pos] = i;
        cnt += (int)__popcll(m);
    }
    __syncthreads();

    int deg = cnt < KNBR ? cnt : KNBR;
    if (lane < KNBR) {
        int e = (lane < deg) ? nbr[lane] : -1;
        out_esrc[d * KNBR + lane] = (float)e;
        out_edst[d * KNBR + lane] = (float)((lane < deg) ? d : -1);
        nbr_i[d * KNBR + lane] = e;
    }
    if (lane == 0) { out_deg[d] = (float)deg; deg_i[d] = deg; }
    if (lane < 3)  out_coord[d * 3 + lane] = coord[id * 3 + lane];
    if (lane == 3) out_batch[d] = (float)batch[id];
}

// K6: scatter-mean of gathered features. One block per dst, one thread per feature dim.
__global__ void agg_kernel(const float* __restrict__ feat,
                           const int* __restrict__ nbr_i, const int* __restrict__ deg_i,
                           int F, float* __restrict__ out_feat) {
    const int d = blockIdx.x;
    const int t = threadIdx.x;  // F threads
    const int deg = deg_i[d];
    float acc = 0.0f;
    for (int k = 0; k < deg; ++k) {
        int nb = nbr_i[d * KNBR + k];
        acc = __fadd_rn(acc, feat[nb * F + t]);
    }
    float den = (float)(deg > 0 ? deg : 1);
    out_feat[d * F + t] = acc / den;
}

extern "C" void kernel_launch(void* const* d_in, const int* in_sizes, int n_in,
                              void* d_out, int out_size, void* d_ws, size_t ws_size,
                              hipStream_t stream) {
    const float* coord = (const float*)d_in[0];
    const float* feat  = (const float*)d_in[1];
    const int*   batch = (const int*)d_in[2];

    const int N      = in_sizes[0] / 3;
    const int F      = in_sizes[1] / N;
    const int n_dst  = N / 4;                 // RATIO = 0.25
    const int nchunk = (N + 63) / 64;         // 313

    // workspace layout (pts 16B-aligned: 4N floats precede it; N=20000 -> 320000 B)
    float*  sx      = (float*)d_ws;
    float*  sy      = sx + N;
    float*  sz      = sy + N;
    float*  sn      = sz + N;
    float4* pts     = (float4*)(sn + N);      // FCAP packed points
    int*    cell      = (int*)(pts + FCAP);
    int*    rank      = cell + N;
    int*    hist      = rank + N;
    int*    cellstart = hist + NCELL;
    int*    idx       = cellstart + NCELL;
    int*    nbr_i     = idx + n_dst;
    int*    deg_i     = nbr_i + n_dst * KNBR;

    // output layout (all float32), reference return order
    float* out     = (float*)d_out;
    float* o_coord = out;                         // n_dst*3
    float* o_feat  = o_coord + (size_t)n_dst * 3; // n_dst*F
    float* o_esrc  = o_feat  + (size_t)n_dst * F; // n_dst*K
    float* o_edst  = o_esrc  + (size_t)n_dst * KNBR;
    float* o_deg   = o_edst  + (size_t)n_dst * KNBR;
    float* o_batch = o_deg   + n_dst;

    hipMemsetAsync(hist, 0, NCELL * sizeof(int), stream);
    prep_kernel<<<(N + 255) / 256, 256, 0, stream>>>(coord, N, sx, sy, sz, sn,
                                                     cell, rank, hist);
    scan_kernel<<<1, 1024, 0, stream>>>(hist, cellstart);
    scatter_kernel<<<(N + 255) / 256, 256, 0, stream>>>(sx, sy, sz, cell, rank,
                                                        cellstart, N, pts);
    pad_kernel<<<(nchunk * 64 - N + 255) / 256, 256, 0, stream>>>(pts, N, nchunk * 64);
    fps_kernel<<<1, FT, 0, stream>>>(pts, coord, nchunk, n_dst, idx);
    ball_kernel<<<n_dst, 64, 0, stream>>>(sx, sy, sz, sn, idx, coord, batch, N, n_dst,
                                          o_coord, o_esrc, o_edst, o_deg, o_batch,
                                          nbr_i, deg_i);
    agg_kernel<<<n_dst, F, 0, stream>>>(feat, nbr_i, deg_i, F, o_feat);
}

// Round 4
// 9497.745 us; speedup vs baseline: 3.1462x; 3.1462x over previous
//
#include <hip/hip_runtime.h>

#define KNBR 32
#define NCELL 4096        // 16^3 Morton cells
#define MAXCHUNK 320      // ceil(20000/64)=313 <= 320
#define FCAP (MAXCHUNK * 64)
#define FT 512            // fps threads: 8 waves (VGPR cap 256 at 2 waves/SIMD)
#define NWAVE (FT / 64)   // 8
#define NSLOT 40          // chunks per wave: 40*8 = 320 >= 313 (clustered mapping)
#define NP 20             // float2 pairs per array
#define NG 5              // slot groups of 8: {0-7,...,32-39}

typedef unsigned long long u64;
typedef unsigned int u32;
typedef float f32x2 __attribute__((ext_vector_type(2)));

// Reference-matching squared distance: ((dx*dx + dy*dy) + dz*dz), no FMA contraction.
__device__ __forceinline__ float sq_dist_nofma(float px, float py, float pz,
                                               float cx, float cy, float cz) {
    float dx = __fsub_rn(px, cx);
    float dy = __fsub_rn(py, cy);
    float dz = __fsub_rn(pz, cz);
    return __fadd_rn(__fadd_rn(__fmul_rn(dx, dx), __fmul_rn(dy, dy)), __fmul_rn(dz, dz));
}

__device__ __forceinline__ unsigned spread4(unsigned v) {
    return (v & 1u) | ((v & 2u) << 2) | ((v & 4u) << 4) | ((v & 8u) << 6);
}

// Canonical CDNA wave64 u32 max-reduction via DPP; lane 63 holds the max;
// readlane broadcasts. Out-of-pattern lanes contribute 0 (identity for unsigned max).
template<int CTRL, int RM>
__device__ __forceinline__ u32 dppmax_step(u32 v) {
    u32 t = (u32)__builtin_amdgcn_update_dpp(0, (int)v, CTRL, RM, 0xf, false);
    return t > v ? t : v;
}
__device__ __forceinline__ u32 wave_max_u32(u32 v) {
    v = dppmax_step<0x111, 0xf>(v);   // row_shr:1
    v = dppmax_step<0x112, 0xf>(v);   // row_shr:2
    v = dppmax_step<0x114, 0xf>(v);   // row_shr:4
    v = dppmax_step<0x118, 0xf>(v);   // row_shr:8
    v = dppmax_step<0x142, 0xa>(v);   // row_bcast:15 -> rows 1,3
    v = dppmax_step<0x143, 0xc>(v);   // row_bcast:31 -> rows 2,3
    return (u32)__builtin_amdgcn_readlane((int)v, 63);
}

// branchless 5-way take
__device__ __forceinline__ void take5(bool t, u32& bh, u32& bl, float& bx, float& by, float& bz,
                                      u32 nh, u32 nl, float nx, float ny, float nz) {
    bh = t ? nh : bh; bl = t ? nl : bl;
    bx = t ? nx : bx; by = t ? ny : by; bz = t ? nz : bz;
}

// K1: AoS -> SoA + norms + Morton cell id + within-cell rank (counting-sort pass 1)
__global__ void prep_kernel(const float* __restrict__ coord, int N,
                            float* __restrict__ sx, float* __restrict__ sy,
                            float* __restrict__ sz, float* __restrict__ sn,
                            int* __restrict__ cell, int* __restrict__ rank,
                            int* __restrict__ hist) {
    int i = blockIdx.x * blockDim.x + threadIdx.x;
    if (i < N) {
        float x = coord[3 * i + 0];
        float y = coord[3 * i + 1];
        float z = coord[3 * i + 2];
        sx[i] = x; sy[i] = y; sz[i] = z;
        sn[i] = __fadd_rn(__fadd_rn(__fmul_rn(x, x), __fmul_rn(y, y)), __fmul_rn(z, z));
        int ix = (int)(x * 16.0f); ix = ix < 0 ? 0 : (ix > 15 ? 15 : ix);
        int iy = (int)(y * 16.0f); iy = iy < 0 ? 0 : (iy > 15 ? 15 : iy);
        int iz = (int)(z * 16.0f); iz = iz < 0 ? 0 : (iz > 15 ? 15 : iz);
        unsigned mc = spread4(ix) | (spread4(iy) << 1) | (spread4(iz) << 2);
        cell[i] = (int)mc;
        rank[i] = atomicAdd(&hist[mc], 1);
    }
}

// K2: exclusive scan of 4096-bin histogram
__global__ __launch_bounds__(1024) void scan_kernel(const int* __restrict__ hist,
                                                    int* __restrict__ cellstart) {
    __shared__ int buf[1024];
    int t = threadIdx.x;
    int h0 = hist[4 * t], h1 = hist[4 * t + 1], h2 = hist[4 * t + 2], h3 = hist[4 * t + 3];
    int s = h0 + h1 + h2 + h3;
    buf[t] = s;
    __syncthreads();
    for (int off = 1; off < 1024; off <<= 1) {
        int v = (t >= off) ? buf[t - off] : 0;
        __syncthreads();
        buf[t] += v;
        __syncthreads();
    }
    int ex = buf[t] - s;
    cellstart[4 * t]     = ex;
    cellstart[4 * t + 1] = ex + h0;
    cellstart[4 * t + 2] = ex + h0 + h1;
    cellstart[4 * t + 3] = ex + h0 + h1 + h2;
}

// K3: scatter into Morton order, packed as (x, y, z, orig_idx_bits)
__global__ void scatter_kernel(const float* __restrict__ sx, const float* __restrict__ sy,
                               const float* __restrict__ sz,
                               const int* __restrict__ cell, const int* __restrict__ rank,
                               const int* __restrict__ cellstart, int N,
                               float4* __restrict__ pts) {
    int i = blockIdx.x * blockDim.x + threadIdx.x;
    if (i < N) {
        int pos = cellstart[cell[i]] + rank[i];
        pts[pos] = make_float4(sx[i], sy[i], sz[i], __int_as_float(i));
    }
}

// K3b: sentinel padding
__global__ void pad_kernel(float4* __restrict__ pts, int N, int cap) {
    int i = N + blockIdx.x * blockDim.x + threadIdx.x;
    if (i < cap) pts[i] = make_float4(1e18f, 1e18f, 1e18f, __int_as_float(0x7fffffff));
}

// K4: chunked FPS, round-16: round-3's fold design with the register budget fixed.
// 8 waves x 40 slots/thread; chunk c = wv*40 + r (clustered); lane's point
// pos = c*64 + lane. State in VGPRs: coords+md as f32x2 pairs (160), po (10),
// per-group fold caches incl. coords (35), accg (10) -> ~215 < 256 cap.
// amdgpu_waves_per_eu(2,2) pins the allocator at the 2-waves/SIMD target so it
// doesn't shrink to 128 and offload state to AGPR/scratch (round-1/3 lesson).
// Per step per wave: refold only changed groups (ballot-OR gate) -> merge NG
// candidates -> ONE 2-phase DPP wave max -> winner lane writes key+coords to
// parity LDS -> barrier -> scalar 8-entry scan with index (NO register arrays,
// ONE wcoord read -- round-3's kk/cc scratch spike removed) -> branchless pk
// dist pass over all 40 slots accumulating change ballots.
// Key: hi = md bits, lo = (0x7FFF-orig)<<17 | pos : max => (max md, min orig);
// sentinels (md=0, lo=pos) never beat any real md>0.
__global__ __launch_bounds__(FT)
__attribute__((amdgpu_waves_per_eu(2, 2)))
void fps_kernel(const float4* __restrict__ pts,
                const float* __restrict__ coord,
                int nchunk, int n_dst, int* __restrict__ out_idx) {
#pragma clang fp contract(off)
    __shared__ u64    wwin[2][NWAVE];
    __shared__ float4 wcoord[2][NWAVE];

    const int tid = threadIdx.x, lane = tid & 63, wv = tid / 64;
    const float c0x = coord[0], c0y = coord[1], c0z = coord[2];
    const u32 BL = (u32)(wv * (NSLOT * 64) + lane);   // pos = BL + r*64

    // ---- register-resident point state ----
    f32x2 px2[NP], py2[NP], pz2[NP], md2[NP];
    u32   po[NP];                       // two 15-bit (0x7FFF-orig) fields; sentinel=0

    #pragma unroll
    for (int i = 0; i < NP; ++i) {
        float xs0 = 0.f, ys0 = 0.f, zs0 = 0.f, ms0 = 0.f; u32 ss0 = 0;
        float xs1 = 0.f, ys1 = 0.f, zs1 = 0.f, ms1 = 0.f; u32 ss1 = 0;
        {
            int r = 2 * i, c = wv * NSLOT + r;
            if (c < nchunk) {
                float4 P = pts[(c << 6) + lane];
                int orig = __float_as_int(P.w);
                xs0 = P.x; ys0 = P.y; zs0 = P.z;
                if (orig != 0x7fffffff) {
                    ss0 = 0x7FFFu - (u32)orig;
                    ms0 = sq_dist_nofma(P.x, P.y, P.z, c0x, c0y, c0z);
                }
            }
        }
        {
            int r = 2 * i + 1, c = wv * NSLOT + r;
            if (c < nchunk) {
                float4 P = pts[(c << 6) + lane];
                int orig = __float_as_int(P.w);
                xs1 = P.x; ys1 = P.y; zs1 = P.z;
                if (orig != 0x7fffffff) {
                    ss1 = 0x7FFFu - (u32)orig;
                    ms1 = sq_dist_nofma(P.x, P.y, P.z, c0x, c0y, c0z);
                }
            }
        }
        px2[i].x = xs0; px2[i].y = xs1;
        py2[i].x = ys0; py2[i].y = ys1;
        pz2[i].x = zs0; pz2[i].y = zs1;
        md2[i].x = ms0; md2[i].y = ms1;
        po[i] = ss0 | (ss1 << 16);
    }

    // per-lane per-group cached argmax (key hi, key lo, coords)
    u32 gh[NG], gl[NG]; float gx[NG], gy[NG], gz[NG];
    u64 accg[NG];
    #pragma unroll
    for (int g = 0; g < NG; ++g) { gh[g] = 0; gl[g] = 0; gx[g] = gy[g] = gz[g] = 0.f;
                                   accg[g] = ~0ull; }   // force full fold at s=1

    if (tid == 0) out_idx[0] = 0;

    int par = 1;
    for (int s = 1; s < n_dst; ++s) {
        // (1) refold changed groups (wave-uniform branches; accg from ballots)
        #pragma unroll
        for (int g = 0; g < NG; ++g) {
            if (accg[g]) {
                const int r0 = g * 8;
                u32 bh = 0, bl = 0; float bx = 0.f, by = 0.f, bz = 0.f;
                #pragma unroll
                for (int r = r0; r < r0 + 8; ++r) {
                    const int i = r >> 1, h = r & 1;
                    u32 nh  = __float_as_uint(h ? md2[i].y : md2[i].x);
                    u32 s15 = h ? (po[i] >> 16) : (po[i] & 0xFFFFu);
                    u32 nl  = (s15 << 17) | (BL + (u32)(r * 64));
                    float nx = h ? px2[i].y : px2[i].x;
                    float ny = h ? py2[i].y : py2[i].x;
                    float nz = h ? pz2[i].y : pz2[i].x;
                    bool t = (nh > bh) || (nh == bh && nl > bl);
                    take5(t, bh, bl, bx, by, bz, nh, nl, nx, ny, nz);
                }
                gh[g] = bh; gl[g] = bl; gx[g] = bx; gy[g] = by; gz[g] = bz;
            }
        }
        // (2) merge NG groups + wave DPP max (unique-winner shortcut on lo word)
        u32 whi = gh[0], wlo = gl[0]; float wx = gx[0], wy = gy[0], wz = gz[0];
        #pragma unroll
        for (int g = 1; g < NG; ++g) {
            bool t = (gh[g] > whi) || (gh[g] == whi && gl[g] > wlo);
            take5(t, whi, wlo, wx, wy, wz, gh[g], gl[g], gx[g], gy[g], gz[g]);
        }
        u32 mhi = wave_max_u32(whi);
        u64 tb = __ballot(whi == mhi);
        u32 mlo;
        if (__popcll(tb) == 1) {
            mlo = (u32)__builtin_amdgcn_readlane((int)wlo, (int)(__ffsll((long long)tb) - 1));
        } else {
            mlo = wave_max_u32(whi == mhi ? wlo : 0u);
        }
        u64 tb2 = __ballot(whi == mhi && wlo == mlo);
        if (lane == (int)(__ffsll((long long)tb2) - 1)) {
            wwin[par][wv]   = ((u64)mhi << 32) | mlo;
            wcoord[par][wv] = make_float4(wx, wy, wz, 0.f);
        }
        __syncthreads();                    // the ONLY barrier per step

        // (3) scalar 8-entry scan with index; ONE wcoord read (no register arrays)
        u64 kb = wwin[par][0]; int wb = 0;
        #pragma unroll
        for (int w2 = 1; w2 < NWAVE; ++w2) {
            u64 t2 = wwin[par][w2];
            if (t2 > kb) { kb = t2; wb = w2; }
        }
        float4 C4 = wcoord[par][wb];
        if (tid == 0) out_idx[s] = (int)(0x7FFFu - (u32)((kb >> 17) & 0x7FFFull));
        par ^= 1;

        // (4) branchless pk dist pass over all 40 slots; accumulate change ballots
        f32x2 nx2; nx2.x = C4.x; nx2.y = C4.x;
        f32x2 ny2; ny2.x = C4.y; ny2.y = C4.y;
        f32x2 nz2; nz2.x = C4.z; nz2.y = C4.z;
        #pragma unroll
        for (int g = 0; g < NG; ++g) accg[g] = 0ull;
        #pragma unroll
        for (int i = 0; i < NP; ++i) {
            f32x2 dx = px2[i] - nx2;
            f32x2 dy = py2[i] - ny2;
            f32x2 dz = pz2[i] - nz2;
            f32x2 dd = (dx * dx + dy * dy) + dz * dz;   // contract(off): exact order
            bool ca = dd.x < md2[i].x;
            bool cb = dd.y < md2[i].y;
            accg[i >> 2] |= __ballot(ca) | __ballot(cb);
            md2[i].x = ca ? dd.x : md2[i].x;
            md2[i].y = cb ? dd.y : md2[i].y;
        }
    }
}

// K5: ball query, one wave per dst. First K in-radius src indices in ascending order.
__global__ void ball_kernel(const float* __restrict__ sx, const float* __restrict__ sy,
                            const float* __restrict__ sz, const float* __restrict__ sn,
                            const int* __restrict__ idx,
                            const float* __restrict__ coord, const int* __restrict__ batch,
                            int N, int n_dst,
                            float* __restrict__ out_coord, float* __restrict__ out_esrc,
                            float* __restrict__ out_edst, float* __restrict__ out_deg,
                            float* __restrict__ out_batch,
                            int* __restrict__ nbr_i, int* __restrict__ deg_i) {
    const int d    = blockIdx.x;
    const int lane = threadIdx.x;   // block of 64
    __shared__ int nbr[KNBR];

    const int id = idx[d];
    const float cx = sx[id], cy = sy[id], cz = sz[id];
    const float dn = sn[id];
    const float RR = (float)(0.08 * 0.08);

    int cnt = 0;
    for (int base = 0; base < N && cnt < KNBR; base += 64) {
        int i = base + lane;
        bool in = false;
        if (i < N) {
            float t     = __fmul_rn(sx[i], cx);
            float inner = __fmaf_rn(sy[i], cy, t);
            inner       = __fmaf_rn(sz[i], cz, inner);
            float d2    = __fsub_rn(__fadd_rn(dn, sn[i]), __fmul_rn(2.0f, inner));
            in = (d2 <= RR);
        }
        unsigned long long m = __ballot(in);
        int pos = cnt + __popcll(m & ((1ull << lane) - 1ull));
        if (in && pos < KNBR) nbr[pos] = i;
        cnt += (int)__popcll(m);
    }
    __syncthreads();

    int deg = cnt < KNBR ? cnt : KNBR;
    if (lane < KNBR) {
        int e = (lane < deg) ? nbr[lane] : -1;
        out_esrc[d * KNBR + lane] = (float)e;
        out_edst[d * KNBR + lane] = (float)((lane < deg) ? d : -1);
        nbr_i[d * KNBR + lane] = e;
    }
    if (lane == 0) { out_deg[d] = (float)deg; deg_i[d] = deg; }
    if (lane < 3)  out_coord[d * 3 + lane] = coord[id * 3 + lane];
    if (lane == 3) out_batch[d] = (float)batch[id];
}

// K6: scatter-mean of gathered features. One block per dst, one thread per feature dim.
__global__ void agg_kernel(const float* __restrict__ feat,
                           const int* __restrict__ nbr_i, const int* __restrict__ deg_i,
                           int F, float* __restrict__ out_feat) {
    const int d = blockIdx.x;
    const int t = threadIdx.x;  // F threads
    const int deg = deg_i[d];
    float acc = 0.0f;
    for (int k = 0; k < deg; ++k) {
        int nb = nbr_i[d * KNBR + k];
        acc = __fadd_rn(acc, feat[nb * F + t]);
    }
    float den = (float)(deg > 0 ? deg : 1);
    out_feat[d * F + t] = acc / den;
}

extern "C" void kernel_launch(void* const* d_in, const int* in_sizes, int n_in,
                              void* d_out, int out_size, void* d_ws, size_t ws_size,
                              hipStream_t stream) {
    const float* coord = (const float*)d_in[0];
    const float* feat  = (const float*)d_in[1];
    const int*   batch = (const int*)d_in[2];

    const int N      = in_sizes[0] / 3;
    const int F      = in_sizes[1] / N;
    const int n_dst  = N / 4;                 // RATIO = 0.25
    const int nchunk = (N + 63) / 64;         // 313

    // workspace layout (pts 16B-aligned: 4N floats precede it; N=20000 -> 320000 B)
    float*  sx      = (float*)d_ws;
    float*  sy      = sx + N;
    float*  sz      = sy + N;
    float*  sn      = sz + N;
    float4* pts     = (float4*)(sn + N);      // FCAP packed points
    int*    cell      = (int*)(pts + FCAP);
    int*    rank      = cell + N;
    int*    hist      = rank + N;
    int*    cellstart = hist + NCELL;
    int*    idx       = cellstart + NCELL;
    int*    nbr_i     = idx + n_dst;
    int*    deg_i     = nbr_i + n_dst * KNBR;

    // output layout (all float32), reference return order
    float* out     = (float*)d_out;
    float* o_coord = out;                         // n_dst*3
    float* o_feat  = o_coord + (size_t)n_dst * 3; // n_dst*F
    float* o_esrc  = o_feat  + (size_t)n_dst * F; // n_dst*K
    float* o_edst  = o_esrc  + (size_t)n_dst * KNBR;
    float* o_deg   = o_edst  + (size_t)n_dst * KNBR;
    float* o_batch = o_deg   + n_dst;

    hipMemsetAsync(hist, 0, NCELL * sizeof(int), stream);
    prep_kernel<<<(N + 255) / 256, 256, 0, stream>>>(coord, N, sx, sy, sz, sn,
                                                     cell, rank, hist);
    scan_kernel<<<1, 1024, 0, stream>>>(hist, cellstart);
    scatter_kernel<<<(N + 255) / 256, 256, 0, stream>>>(sx, sy, sz, cell, rank,
                                                        cellstart, N, pts);
    pad_kernel<<<(nchunk * 64 - N + 255) / 256, 256, 0, stream>>>(pts, N, nchunk * 64);
    fps_kernel<<<1, FT, 0, stream>>>(pts, coord, nchunk, n_dst, idx);
    ball_kernel<<<n_dst, 64, 0, stream>>>(sx, sy, sz, sn, idx, coord, batch, N, n_dst,
                                          o_coord, o_esrc, o_edst, o_deg, o_batch,
                                          nbr_i, deg_i);
    agg_kernel<<<n_dst, F, 0, stream>>>(feat, nbr_i, deg_i, F, o_feat);
}